// Round 9
// baseline (112.663 us; speedup 1.0000x reference)
//
#include <hip/hip_runtime.h>

typedef __bf16 bf16_t;
typedef bf16_t bf16x4 __attribute__((ext_vector_type(4)));
typedef bf16_t bf16x8 __attribute__((ext_vector_type(8)));
typedef float f32x4 __attribute__((ext_vector_type(4)));

#define INFV 10000.0f

// ---------------- kernel 0: w1 (1024x128 f32) -> w1T (128x1024 bf16) ----------------
__global__ __launch_bounds__(256) void k0_transpose(const float* __restrict__ w1,
                                                    bf16_t* __restrict__ w1T) {
    __shared__ float s[32][36];
    const int t = threadIdx.x;
    const int k0 = (blockIdx.x & 31) * 32;  // 1024/32
    const int c0 = (blockIdx.x >> 5) * 32;  // 128/32
    {
        const int r = t >> 3, cc = (t & 7) * 4;
        *(float4*)&s[r][cc] = *(const float4*)&w1[(size_t)(k0 + r) * 128 + c0 + cc];
    }
    __syncthreads();
    {
        const int cr = t >> 3, kk = (t & 7) * 4;
        bf16x4 v;
        v[0] = (bf16_t)s[kk + 0][cr];
        v[1] = (bf16_t)s[kk + 1][cr];
        v[2] = (bf16_t)s[kk + 2][cr];
        v[3] = (bf16_t)s[kk + 3][cr];
        *(bf16x4*)&w1T[(size_t)(c0 + cr) * 1024 + k0 + kk] = v;
    }
}

// ---------------- kernel 1: INSTRUMENTATION — R2 body repeated 5x ----------------
// Identical work each rep (idempotent, deterministic). 5x duration pushes this
// kernel into rocprof's top-5 so we finally see its counters. Per-rep metrics =
// totals / 5; rate counters (VALUBusy, MfmaUtil, Occupancy) read directly.
__global__ __launch_bounds__(256) void k1_proj(
    const float* __restrict__ inputs,   // [8192][1024]
    const bf16_t* __restrict__ w1T,     // [128][1024] bf16
    const float* __restrict__ b1,       // [128]
    const float* __restrict__ w2,       // [128][24]
    const float* __restrict__ b2,       // [24]
    bf16_t* __restrict__ qg,            // [8192][64] bf16
    bf16_t* __restrict__ kg,            // [8192][64] bf16
    float* __restrict__ biasT)          // [16][24][512]
{
    __shared__ bf16_t s_a[16][72];      // 16 rows x 64 k (pad 8)
    __shared__ float s_x[16][132];
    __shared__ float s_w2T[24][132];

    const int t = threadIdx.x;
    const int row0 = blockIdx.x * 16;
    const int lane = t & 63, wave = t >> 6;
    const int cn = lane & 15, kgrp = lane >> 4;

    // stage w2^T once (reps only read it)
    for (int i = t; i < 3072; i += 256) {
        int j = i / 24, c = i - j * 24;
        s_w2T[c][j] = w2[i];
    }

    for (int rep = 0; rep < 5; ++rep) {

    f32x4 acc[2] = {};
    const int sr = t >> 4;          // 0..15
    const int sc = (t & 15) * 4;    // 0..60
    float4 pf = *(const float4*)&inputs[(size_t)(row0 + sr) * 1024 + sc];

    for (int ks = 0; ks < 16; ++ks) {
        const int k0 = ks * 64;
        {
            bf16x4 v;
            v[0] = (bf16_t)pf.x; v[1] = (bf16_t)pf.y; v[2] = (bf16_t)pf.z; v[3] = (bf16_t)pf.w;
            *(bf16x4*)&s_a[sr][sc] = v;
        }
        __syncthreads();
        if (ks < 15)
            pf = *(const float4*)&inputs[(size_t)(row0 + sr) * 1024 + k0 + 64 + sc];
        bf16x8 a0 = *(const bf16x8*)&s_a[cn][kgrp * 8];
        bf16x8 a1 = *(const bf16x8*)&s_a[cn][32 + kgrp * 8];
#pragma unroll
        for (int tt = 0; tt < 2; ++tt) {
            const int col = wave * 32 + tt * 16 + cn;
            const bf16_t* wp = w1T + (size_t)col * 1024 + k0 + kgrp * 8;
            bf16x8 bb0 = *(const bf16x8*)wp;
            bf16x8 bb1 = *(const bf16x8*)(wp + 32);
            acc[tt] = __builtin_amdgcn_mfma_f32_16x16x32_bf16(a0, bb0, acc[tt], 0, 0, 0);
            acc[tt] = __builtin_amdgcn_mfma_f32_16x16x32_bf16(a1, bb1, acc[tt], 0, 0, 0);
        }
        __syncthreads();
    }

    {
        const int rgrp = lane >> 4;
#pragma unroll
        for (int tt = 0; tt < 2; ++tt) {
            const int col = wave * 32 + tt * 16 + cn;
            const float bb = b1[col];
#pragma unroll
            for (int r = 0; r < 4; ++r)
                s_x[rgrp * 4 + r][col] = acc[tt][r] + bb;
        }
    }
    __syncthreads();

    {
        const int r = t >> 4;
        const int i0 = (t & 15) * 2;
        const int rowg = row0 + r;
        const int n = rowg & 511;
        bf16x4 qv, kv;
#pragma unroll
        for (int u = 0; u < 2; ++u) {
            const int i = i0 + u;
            float fr = (float)n * exp2f((float)i * -0.4152410118609203f);
            float sv, cv;
            sincosf(fr, &sv, &cv);
            float x0 = s_x[r][4 * i + 0];
            float x1 = s_x[r][4 * i + 1];
            float x2 = s_x[r][4 * i + 2];
            float x3 = s_x[r][4 * i + 3];
            qv[2 * u]     = (bf16_t)(x0 * cv - x2 * sv);
            qv[2 * u + 1] = (bf16_t)(x0 * sv + x2 * cv);
            kv[2 * u]     = (bf16_t)(x1 * cv - x3 * sv);
            kv[2 * u + 1] = (bf16_t)(x1 * sv + x3 * cv);
        }
        *(bf16x4*)&qg[(size_t)rowg * 64 + 2 * i0] = qv;
        *(bf16x4*)&kg[(size_t)rowg * 64 + 2 * i0] = kv;
    }

    {
        const int r = t >> 4;
        const int cb = t & 15;
        if (cb < 12) {
            const int c0 = cb * 2;
            float sum0 = 0.f, sum1 = 0.f;
#pragma unroll 4
            for (int j = 0; j < 128; j += 4) {
                float4 xv = *(const float4*)&s_x[r][j];
                float4 wa = *(const float4*)&s_w2T[c0 + 0][j];
                float4 wb = *(const float4*)&s_w2T[c0 + 1][j];
                sum0 += xv.x * wa.x + xv.y * wa.y + xv.z * wa.z + xv.w * wa.w;
                sum1 += xv.x * wb.x + xv.y * wb.y + xv.z * wb.z + xv.w * wb.w;
            }
            const int rowg = row0 + r;
            const int bb = rowg >> 9, n = rowg & 511;
            float* bp = biasT + (size_t)bb * 12288 + n;
            bp[(size_t)(c0 + 0) * 512] = (sum0 + b2[c0 + 0]) * 0.5f;
            bp[(size_t)(c0 + 1) * 512] = (sum1 + b2[c0 + 1]) * 0.5f;
        }
    }

    __syncthreads();   // isolate reps (s_x WAR safety)
    }  // rep
}

// ---------------- kernel 2: exact R2 version ----------------
__global__ __launch_bounds__(256) void k2_logits(
    const bf16_t* __restrict__ qg, const bf16_t* __restrict__ kg,
    const float* __restrict__ biasT, const int* __restrict__ am,
    float* __restrict__ out)
{
    __shared__ float s_be[12][64], s_bo[12][64];
    __shared__ float s_pm[64], s_pn[64];

    const int t = threadIdx.x;
    const int b = blockIdx.z;
    const int m0 = blockIdx.y * 64;
    const int n0 = blockIdx.x * 64;

    for (int i = t; i < 768; i += 256) {
        const int h = i >> 6, j = i & 63;
        s_be[h][j] = biasT[(size_t)b * 12288 + (size_t)(2 * h) * 512 + n0 + j];
        s_bo[h][j] = biasT[(size_t)b * 12288 + (size_t)(2 * h + 1) * 512 + m0 + j];
    }
    if (t < 64) s_pm[t] = (float)am[b * 512 + m0 + t];
    else if (t < 128) s_pn[t - 64] = (float)am[b * 512 + n0 + (t - 64)];

    const int lane = t & 63, wave = t >> 6;
    const int cn = lane & 15, kgrp = lane >> 4;

    const bf16_t* qp = qg + ((size_t)(b * 512 + m0 + wave * 16 + cn)) * 64 + kgrp * 8;
    bf16x8 qb0 = *(const bf16x8*)qp;
    bf16x8 qb1 = *(const bf16x8*)(qp + 32);

    f32x4 acc[4] = {};
#pragma unroll
    for (int nt = 0; nt < 4; ++nt) {
        const bf16_t* kp = kg + ((size_t)(b * 512 + n0 + nt * 16 + cn)) * 64 + kgrp * 8;
        bf16x8 ka0 = *(const bf16x8*)kp;
        bf16x8 ka1 = *(const bf16x8*)(kp + 32);
        acc[nt] = __builtin_amdgcn_mfma_f32_16x16x32_bf16(ka0, qb0, acc[nt], 0, 0, 0);
        acc[nt] = __builtin_amdgcn_mfma_f32_16x16x32_bf16(ka1, qb1, acc[nt], 0, 0, 0);
    }
    __syncthreads();

    const int rgrp = lane >> 4;
    const int m_loc = wave * 16 + cn;
    const int m = m0 + m_loc;
    const float am_m = s_pm[m_loc];

#pragma unroll
    for (int nt = 0; nt < 4; ++nt) {
#pragma unroll
        for (int r = 0; r < 4; ++r) {
            const int n_loc = nt * 16 + rgrp * 4 + r;
            float v = acc[nt][r] * 0.125f;
            v -= (1.0f - am_m * s_pn[n_loc]) * INFV;
            if (m > n0 + n_loc) v -= INFV;
            acc[nt][r] = v;
        }
    }

    float* ob = out + (size_t)b * 3145728 + (size_t)m * 512 + n0;
#pragma unroll
    for (int h = 0; h < 12; ++h) {
        const float bo = s_bo[h][m_loc];
        const f32x4 bov = {bo, bo, bo, bo};
#pragma unroll
        for (int nt = 0; nt < 4; ++nt) {
            const f32x4 be4 = *(const f32x4*)&s_be[h][nt * 16 + rgrp * 4];
            f32x4 w = acc[nt] + be4 + bov;
            *(f32x4*)&ob[(size_t)h * 262144 + nt * 16 + rgrp * 4] = w;
        }
    }
}

extern "C" void kernel_launch(void* const* d_in, const int* in_sizes, int n_in,
                              void* d_out, int out_size, void* d_ws, size_t ws_size,
                              hipStream_t stream) {
    const float* inputs = (const float*)d_in[0];
    const int*   am     = (const int*)d_in[1];
    const float* w1     = (const float*)d_in[2];
    const float* b1     = (const float*)d_in[3];
    const float* w2     = (const float*)d_in[4];
    const float* b2     = (const float*)d_in[5];
    float* out = (float*)d_out;

    bf16_t* w1T   = (bf16_t*)d_ws;           // 128*1024 bf16   = 256 KB
    bf16_t* qg    = w1T + 131072;            // 8192*64 bf16    = 1 MB
    bf16_t* kg    = qg + 524288;             // 8192*64 bf16    = 1 MB
    float*  biasT = (float*)(kg + 524288);   // 16*24*512 f32   = 768 KB

    k0_transpose<<<128, 256, 0, stream>>>(w1, w1T);
    k1_proj<<<512, 256, 0, stream>>>(inputs, w1T, b1, w2, b2, qg, kg, biasT);
    k2_logits<<<dim3(8, 8, 16), 256, 0, stream>>>(qg, kg, biasT, am, out);
}

// Round 10
// 67.018 us; speedup vs baseline: 1.6811x; 1.6811x over previous
//
#include <hip/hip_runtime.h>

typedef __bf16 bf16_t;
typedef bf16_t bf16x4 __attribute__((ext_vector_type(4)));
typedef bf16_t bf16x8 __attribute__((ext_vector_type(8)));
typedef float f32x4 __attribute__((ext_vector_type(4)));

#define INFV 10000.0f

// ---------------- kernel 0: w1 (1024x128 f32) -> w1T (128x1024 bf16) ----------------
__global__ __launch_bounds__(256) void k0_transpose(const float* __restrict__ w1,
                                                    bf16_t* __restrict__ w1T) {
    __shared__ float s[32][36];
    const int t = threadIdx.x;
    const int k0 = (blockIdx.x & 31) * 32;  // 1024/32
    const int c0 = (blockIdx.x >> 5) * 32;  // 128/32
    {
        const int r = t >> 3, cc = (t & 7) * 4;
        *(float4*)&s[r][cc] = *(const float4*)&w1[(size_t)(k0 + r) * 128 + c0 + cc];
    }
    __syncthreads();
    {
        const int cr = t >> 3, kk = (t & 7) * 4;
        bf16x4 v;
        v[0] = (bf16_t)s[kk + 0][cr];
        v[1] = (bf16_t)s[kk + 1][cr];
        v[2] = (bf16_t)s[kk + 2][cr];
        v[3] = (bf16_t)s[kk + 3][cr];
        *(bf16x4*)&w1T[(size_t)(c0 + cr) * 1024 + k0 + kk] = v;
    }
}

// ---------------- kernel 1 v7: 256 blocks x 512 thr (1 block/CU, 32 rows x 128 cols)
// dbuf LDS (1 barrier/step), B prefetched 1 step ahead (regs), A prefetched 2
// steps ahead, parity-split accumulators. Fully unrolled -> static reg indices.
__global__ __launch_bounds__(512) void k1_proj(
    const float* __restrict__ inputs,   // [8192][1024]
    const bf16_t* __restrict__ w1T,     // [128][1024] bf16
    const float* __restrict__ b1,       // [128]
    const float* __restrict__ w2,       // [128][24]
    const float* __restrict__ b2,       // [24]
    bf16_t* __restrict__ qg,            // [8192][64] bf16
    bf16_t* __restrict__ kg,            // [8192][64] bf16
    float* __restrict__ biasT)          // [16][24][512]
{
    __shared__ bf16_t s_a[2][32][72];   // dbuf: 32 rows x 64 k (pad 8) x 2
    __shared__ float s_x[32][132];
    __shared__ float s_w2T[24][132];

    const int t = threadIdx.x;
    const int row0 = blockIdx.x * 32;
    const int lane = t & 63, wave = t >> 6;      // 8 waves
    const int cn = lane & 15, kgrp = lane >> 4;
    const int rg = (wave & 1) * 16;              // row-group base (0/16)
    const int cg = (wave >> 1) * 32;             // col-group base (0/32/64/96)

    // stage w2^T (consumed after the epilogue barrier)
    for (int i = t; i < 3072; i += 512) {
        int j = i / 24, c = i - j * 24;
        s_w2T[c][j] = w2[i];
    }

    // staging coords: one f32x4 per thread per K-step (32 rows x 64 cols)
    const int sr = t >> 4;            // 0..31
    const int sc = (t & 15) * 4;      // 0..60
    const float* asrc = inputs + (size_t)(row0 + sr) * 1024 + sc;

    const bf16_t* bp0 = w1T + (size_t)(cg + 0 * 16 + cn) * 1024 + kgrp * 8;
    const bf16_t* bp1 = w1T + (size_t)(cg + 1 * 16 + cn) * 1024 + kgrp * 8;

    f32x4 acc[2][2] = {};             // [tt][parity]
    float4 pfA[2];
    bf16x8 bfr[2][2][2];              // [buf][tt][half]

    // prologue: stage step 0, prefetch A(1),A(2), B(0)
    {
        float4 v = *(const float4*)(asrc);
        bf16x4 b;
        b[0] = (bf16_t)v.x; b[1] = (bf16_t)v.y; b[2] = (bf16_t)v.z; b[3] = (bf16_t)v.w;
        *(bf16x4*)&s_a[0][sr][sc] = b;
    }
    pfA[1] = *(const float4*)(asrc + 64);    // A(1) -> slot 1&1
    pfA[0] = *(const float4*)(asrc + 128);   // A(2) -> slot 2&1
    bfr[0][0][0] = *(const bf16x8*)(bp0 + 0);
    bfr[0][0][1] = *(const bf16x8*)(bp0 + 32);
    bfr[0][1][0] = *(const bf16x8*)(bp1 + 0);
    bfr[0][1][1] = *(const bf16x8*)(bp1 + 32);
    __syncthreads();

#pragma unroll
    for (int kt = 0; kt < 16; ++kt) {
        const int p = kt & 1;
        // issue next-step B loads (hidden under MFMA + ds_write + barrier)
        if (kt < 15) {
            const int o = (kt + 1) * 64;
            bfr[p ^ 1][0][0] = *(const bf16x8*)(bp0 + o);
            bfr[p ^ 1][0][1] = *(const bf16x8*)(bp0 + o + 32);
            bfr[p ^ 1][1][0] = *(const bf16x8*)(bp1 + o);
            bfr[p ^ 1][1][1] = *(const bf16x8*)(bp1 + o + 32);
        }
        // compute current step from buf p
        {
            bf16x8 af0 = *(const bf16x8*)&s_a[p][rg + cn][kgrp * 8];
            bf16x8 af1 = *(const bf16x8*)&s_a[p][rg + cn][32 + kgrp * 8];
            acc[0][p] = __builtin_amdgcn_mfma_f32_16x16x32_bf16(af0, bfr[p][0][0], acc[0][p], 0, 0, 0);
            acc[0][p] = __builtin_amdgcn_mfma_f32_16x16x32_bf16(af1, bfr[p][0][1], acc[0][p], 0, 0, 0);
            acc[1][p] = __builtin_amdgcn_mfma_f32_16x16x32_bf16(af0, bfr[p][1][0], acc[1][p], 0, 0, 0);
            acc[1][p] = __builtin_amdgcn_mfma_f32_16x16x32_bf16(af1, bfr[p][1][1], acc[1][p], 0, 0, 0);
        }
        // write next step's A tile (loaded 2 steps ago) into the other buffer
        if (kt < 15) {
            float4 v = pfA[(kt + 1) & 1];
            bf16x4 b;
            b[0] = (bf16_t)v.x; b[1] = (bf16_t)v.y; b[2] = (bf16_t)v.z; b[3] = (bf16_t)v.w;
            *(bf16x4*)&s_a[p ^ 1][sr][sc] = b;
        }
        // issue A load 3 steps ahead (2 full steps in flight)
        if (kt < 13) {
            pfA[(kt + 3) & 1] = *(const float4*)(asrc + (kt + 3) * 64);
        }
        __syncthreads();
    }

    // epilogue: x (+b1) -> LDS. D: input-row = rg + kgrp*4 + r, col = cg + tt*16 + cn
#pragma unroll
    for (int tt = 0; tt < 2; ++tt) {
        const int col = cg + tt * 16 + cn;
        const float bb = b1[col];
        f32x4 sum = acc[tt][0] + acc[tt][1];
#pragma unroll
        for (int r = 0; r < 4; ++r)
            s_x[rg + kgrp * 4 + r][col] = sum[r] + bb;
    }
    __syncthreads();

    // rope -> qg, kg: r = t>>4 (0..31), 2 freq-indices each
    {
        const int r = t >> 4;
        const int i0 = (t & 15) * 2;
        const int rowg = row0 + r;
        const int n = rowg & 511;
        bf16x4 qv, kv;
#pragma unroll
        for (int u = 0; u < 2; ++u) {
            const int i = i0 + u;
            float fr = (float)n * exp2f((float)i * -0.4152410118609203f);
            float sv, cv;
            sincosf(fr, &sv, &cv);
            float x0 = s_x[r][4 * i + 0];
            float x1 = s_x[r][4 * i + 1];
            float x2 = s_x[r][4 * i + 2];
            float x3 = s_x[r][4 * i + 3];
            qv[2 * u]     = (bf16_t)(x0 * cv - x2 * sv);
            qv[2 * u + 1] = (bf16_t)(x0 * sv + x2 * cv);
            kv[2 * u]     = (bf16_t)(x1 * cv - x3 * sv);
            kv[2 * u + 1] = (bf16_t)(x1 * sv + x3 * cv);
        }
        *(bf16x4*)&qg[(size_t)rowg * 64 + 2 * i0] = qv;
        *(bf16x4*)&kg[(size_t)rowg * 64 + 2 * i0] = kv;
    }

    // bias: (x @ w2 + b2) * 0.5 -> biasT[b][c][n]; r = t>>4, 2 cols per thread
    {
        const int r = t >> 4;
        const int cb = t & 15;
        if (cb < 12) {
            const int c0 = cb * 2;
            float sum0 = 0.f, sum1 = 0.f;
#pragma unroll 4
            for (int j = 0; j < 128; j += 4) {
                float4 xv = *(const float4*)&s_x[r][j];
                float4 wa = *(const float4*)&s_w2T[c0 + 0][j];
                float4 wb = *(const float4*)&s_w2T[c0 + 1][j];
                sum0 += xv.x * wa.x + xv.y * wa.y + xv.z * wa.z + xv.w * wa.w;
                sum1 += xv.x * wb.x + xv.y * wb.y + xv.z * wb.z + xv.w * wb.w;
            }
            const int rowg = row0 + r;
            const int bb = rowg >> 9, n = rowg & 511;
            float* bp = biasT + (size_t)bb * 12288 + n;
            bp[(size_t)(c0 + 0) * 512] = (sum0 + b2[c0 + 0]) * 0.5f;
            bp[(size_t)(c0 + 1) * 512] = (sum1 + b2[c0 + 1]) * 0.5f;
        }
    }
}

// ---------------- kernel 2: exact R2 version ----------------
__global__ __launch_bounds__(256) void k2_logits(
    const bf16_t* __restrict__ qg, const bf16_t* __restrict__ kg,
    const float* __restrict__ biasT, const int* __restrict__ am,
    float* __restrict__ out)
{
    __shared__ float s_be[12][64], s_bo[12][64];
    __shared__ float s_pm[64], s_pn[64];

    const int t = threadIdx.x;
    const int b = blockIdx.z;
    const int m0 = blockIdx.y * 64;
    const int n0 = blockIdx.x * 64;

    for (int i = t; i < 768; i += 256) {
        const int h = i >> 6, j = i & 63;
        s_be[h][j] = biasT[(size_t)b * 12288 + (size_t)(2 * h) * 512 + n0 + j];
        s_bo[h][j] = biasT[(size_t)b * 12288 + (size_t)(2 * h + 1) * 512 + m0 + j];
    }
    if (t < 64) s_pm[t] = (float)am[b * 512 + m0 + t];
    else if (t < 128) s_pn[t - 64] = (float)am[b * 512 + n0 + (t - 64)];

    const int lane = t & 63, wave = t >> 6;
    const int cn = lane & 15, kgrp = lane >> 4;

    const bf16_t* qp = qg + ((size_t)(b * 512 + m0 + wave * 16 + cn)) * 64 + kgrp * 8;
    bf16x8 qb0 = *(const bf16x8*)qp;
    bf16x8 qb1 = *(const bf16x8*)(qp + 32);

    f32x4 acc[4] = {};
#pragma unroll
    for (int nt = 0; nt < 4; ++nt) {
        const bf16_t* kp = kg + ((size_t)(b * 512 + n0 + nt * 16 + cn)) * 64 + kgrp * 8;
        bf16x8 ka0 = *(const bf16x8*)kp;
        bf16x8 ka1 = *(const bf16x8*)(kp + 32);
        acc[nt] = __builtin_amdgcn_mfma_f32_16x16x32_bf16(ka0, qb0, acc[nt], 0, 0, 0);
        acc[nt] = __builtin_amdgcn_mfma_f32_16x16x32_bf16(ka1, qb1, acc[nt], 0, 0, 0);
    }
    __syncthreads();

    const int rgrp = lane >> 4;
    const int m_loc = wave * 16 + cn;
    const int m = m0 + m_loc;
    const float am_m = s_pm[m_loc];

#pragma unroll
    for (int nt = 0; nt < 4; ++nt) {
#pragma unroll
        for (int r = 0; r < 4; ++r) {
            const int n_loc = nt * 16 + rgrp * 4 + r;
            float v = acc[nt][r] * 0.125f;
            v -= (1.0f - am_m * s_pn[n_loc]) * INFV;
            if (m > n0 + n_loc) v -= INFV;
            acc[nt][r] = v;
        }
    }

    float* ob = out + (size_t)b * 3145728 + (size_t)m * 512 + n0;
#pragma unroll
    for (int h = 0; h < 12; ++h) {
        const float bo = s_bo[h][m_loc];
        const f32x4 bov = {bo, bo, bo, bo};
#pragma unroll
        for (int nt = 0; nt < 4; ++nt) {
            const f32x4 be4 = *(const f32x4*)&s_be[h][nt * 16 + rgrp * 4];
            f32x4 w = acc[nt] + be4 + bov;
            *(f32x4*)&ob[(size_t)h * 262144 + nt * 16 + rgrp * 4] = w;
        }
    }
}

extern "C" void kernel_launch(void* const* d_in, const int* in_sizes, int n_in,
                              void* d_out, int out_size, void* d_ws, size_t ws_size,
                              hipStream_t stream) {
    const float* inputs = (const float*)d_in[0];
    const int*   am     = (const int*)d_in[1];
    const float* w1     = (const float*)d_in[2];
    const float* b1     = (const float*)d_in[3];
    const float* w2     = (const float*)d_in[4];
    const float* b2     = (const float*)d_in[5];
    float* out = (float*)d_out;

    bf16_t* w1T   = (bf16_t*)d_ws;           // 128*1024 bf16   = 256 KB
    bf16_t* qg    = w1T + 131072;            // 8192*64 bf16    = 1 MB
    bf16_t* kg    = qg + 524288;             // 8192*64 bf16    = 1 MB
    float*  biasT = (float*)(kg + 524288);   // 16*24*512 f32   = 768 KB

    k0_transpose<<<128, 256, 0, stream>>>(w1, w1T);
    k1_proj<<<256, 512, 0, stream>>>(inputs, w1T, b1, w2, b2, qg, kg, biasT);
    k2_logits<<<dim3(8, 8, 16), 256, 0, stream>>>(qg, kg, biasT, am, out);
}